// Round 1
// baseline (354.297 us; speedup 1.0000x reference)
//
#include <hip/hip_runtime.h>

typedef __attribute__((ext_vector_type(8))) short short8;
typedef __attribute__((ext_vector_type(4))) float f32x4;
typedef __attribute__((ext_vector_type(4))) int i32x4;

__device__ __forceinline__ unsigned short f2bf(float f) {
  unsigned u = __builtin_bit_cast(unsigned, f);
  u += 0x7fffu + ((u >> 16) & 1u);
  return (unsigned short)(u >> 16);
}

// ---------------- convert hidden_states fp32 -> bf16 ----------------
__global__ __launch_bounds__(256) void k_convert(const float* __restrict__ x,
                                                 unsigned short* __restrict__ y) {
  int i = blockIdx.x * 256 + threadIdx.x;   // one thread = 8 elements, exact
  const float* p = x + (size_t)i * 8;
  f32x4 a = *(const f32x4*)p;
  f32x4 b = *(const f32x4*)(p + 4);
  unsigned short o[8];
  o[0] = f2bf(a[0]); o[1] = f2bf(a[1]); o[2] = f2bf(a[2]); o[3] = f2bf(a[3]);
  o[4] = f2bf(b[0]); o[5] = f2bf(b[1]); o[6] = f2bf(b[2]); o[7] = f2bf(b[3]);
  short8 v;
  #pragma unroll
  for (int j = 0; j < 8; ++j) v[j] = (short)o[j];
  *(short8*)(y + (size_t)i * 8) = v;
}

// ---------------- prep: Wt[1152][384] bf16 (transposed, fused QKV), bias[1152] ----------------
__global__ __launch_bounds__(256) void k_prepw(const float* __restrict__ Wq, const float* __restrict__ Wk,
                                               const float* __restrict__ Wv, const float* __restrict__ bq,
                                               const float* __restrict__ bk, const float* __restrict__ bv,
                                               unsigned short* __restrict__ Wt, float* __restrict__ bvec) {
  int i = blockIdx.x * 256 + threadIdx.x;   // 1152*384 = 442368 exact
  int n = i / 384, k = i - n * 384;
  int which = n / 384;                      // 0..2
  int c = n - which * 384;
  const float* W = (which == 0) ? Wq : (which == 1) ? Wk : Wv;
  Wt[i] = f2bf(W[k * 384 + c]);
  if (k == 0) {
    const float* bb = (which == 0) ? bq : (which == 1) ? bk : bv;
    bvec[n] = bb[c];
  }
}

// ---------------- prep: bias12[h][q][k] = table[rel_index[q][k]][h] ----------------
__global__ __launch_bounds__(256) void k_prepb(const float* __restrict__ tab, const int* __restrict__ ridx,
                                               float* __restrict__ b12) {
  int i = blockIdx.x * 256 + threadIdx.x;
  if (i >= 12 * 2401) return;
  int h = i / 2401, qk = i - h * 2401;
  b12[i] = tab[ridx[qk] * 12 + h];
}

// ---------------- QKV GEMM: X[50176,384]bf16 @ Wt^T -> Q,K,V [B,H,S,D] bf16 ----------------
#define GLDA 40
__global__ __launch_bounds__(256) void k_qkv(const unsigned short* __restrict__ X,
                                             const unsigned short* __restrict__ Wt,
                                             const float* __restrict__ bvec,
                                             unsigned short* __restrict__ Qo,
                                             unsigned short* __restrict__ Ko,
                                             unsigned short* __restrict__ Vo) {
  __shared__ __align__(16) unsigned short As[128 * GLDA];
  __shared__ __align__(16) unsigned short Bs[128 * GLDA];
  int orig = blockIdx.x;                       // 3528 = 8 * 441
  int wg = (orig & 7) * 441 + (orig >> 3);     // XCD-chunked swizzle (bijective)
  int bm = wg / 9, bn = wg - (wg / 9) * 9;
  int tid = threadIdx.x;
  int lr = tid >> 1, lc = (tid & 1) * 16;
  const unsigned short* Ag = X + (size_t)(bm * 128 + lr) * 384 + lc;
  const unsigned short* Bg = Wt + (size_t)(bn * 128 + lr) * 384 + lc;
  unsigned short* Asw = &As[lr * GLDA + lc];
  unsigned short* Bsw = &Bs[lr * GLDA + lc];
  int lane = tid & 63, wid = tid >> 6;
  int moff = (wid >> 1) * 64, noff = (wid & 1) * 64;
  int lrow = lane & 15, lgrp = lane >> 4;
  f32x4 acc[4][4] = {};
  for (int ks = 0; ks < 12; ++ks) {
    __syncthreads();
    *(i32x4*)Asw       = *(const i32x4*)(Ag + ks * 32);
    *(i32x4*)(Asw + 8) = *(const i32x4*)(Ag + ks * 32 + 8);
    *(i32x4*)Bsw       = *(const i32x4*)(Bg + ks * 32);
    *(i32x4*)(Bsw + 8) = *(const i32x4*)(Bg + ks * 32 + 8);
    __syncthreads();
    short8 a[4], b[4];
    #pragma unroll
    for (int i = 0; i < 4; ++i) a[i] = *(const short8*)&As[(moff + i * 16 + lrow) * GLDA + lgrp * 8];
    #pragma unroll
    for (int i = 0; i < 4; ++i) b[i] = *(const short8*)&Bs[(noff + i * 16 + lrow) * GLDA + lgrp * 8];
    #pragma unroll
    for (int i = 0; i < 4; ++i)
      #pragma unroll
      for (int j = 0; j < 4; ++j)
        acc[i][j] = __builtin_amdgcn_mfma_f32_16x16x32_bf16(a[i], b[j], acc[i][j], 0, 0, 0);
  }
  // epilogue: n-range of this block lies entirely inside one of Q/K/V (384 = 3*128)
  int which = bn / 3;
  unsigned short* Dst = (which == 0) ? Qo : (which == 1) ? Ko : Vo;
  int nbase = bn * 128 - which * 384;
  float scale = (which == 0) ? 0.17677669529663687f : 1.0f;
  #pragma unroll
  for (int i = 0; i < 4; ++i) {
    #pragma unroll
    for (int j2 = 0; j2 < 4; ++j2) {
      int row = moff + i * 16 + lgrp * 4 + j2;
      int gm = bm * 128 + row;
      int bb = gm / 49, ss = gm - bb * 49;
      #pragma unroll
      for (int j = 0; j < 4; ++j) {
        int n = nbase + noff + j * 16 + lrow;   // 0..383 within q/k/v
        int h = n >> 5, d = n & 31;
        float val = (acc[i][j][j2] + bvec[which * 384 + n]) * scale;
        Dst[((size_t)(bb * 12 + h) * 49 + ss) * 32 + d] = f2bf(val);
      }
    }
  }
}

// ---------------- attention: one wave per (b,h); S=49 padded to 64 ----------------
__global__ __launch_bounds__(64) void k_attn(const unsigned short* __restrict__ Qb,
                                             const unsigned short* __restrict__ Kb,
                                             const unsigned short* __restrict__ Vb,
                                             const float* __restrict__ b12,
                                             const float* __restrict__ msk,
                                             float* __restrict__ out) {
  __shared__ __align__(16) unsigned short pool[64 * 40 * 2 + 32 * 72];
  unsigned short* Qs = pool;            // [64][40]
  unsigned short* Ks = pool + 2560;     // [64][40]
  unsigned short* Vt = pool + 5120;     // [32][72]  (V transposed: Vt[d][s])
  unsigned short* Ps = pool;            // [64][72]  overlays Qs+Ks (4608 <= 5120)
  int bh = blockIdx.x;
  int b = bh / 12, h = bh - b * 12;
  int lane = threadIdx.x;
  int lrow = lane & 15, lgrp = lane >> 4;
  const unsigned short* Qg = Qb + (size_t)bh * 1568;
  const unsigned short* Kg = Kb + (size_t)bh * 1568;
  const unsigned short* Vg = Vb + (size_t)bh * 1568;

  // zero Vt
  i32x4 z = {0, 0, 0, 0};
  for (int c = lane; c < 32 * 72 / 8; c += 64) *(i32x4*)&Vt[c * 8] = z;
  // stage Q,K zero-padded; V transposed
  for (int c = lane; c < 256; c += 64) {
    int r = c >> 2, c8 = (c & 3) * 8;
    i32x4 qv = z, kv = z;
    if (r < 49) {
      qv = *(const i32x4*)(Qg + r * 32 + c8);
      kv = *(const i32x4*)(Kg + r * 32 + c8);
      short8 vv = *(const short8*)(Vg + r * 32 + c8);
      #pragma unroll
      for (int j = 0; j < 8; ++j) Vt[(c8 + j) * 72 + r] = (unsigned short)vv[j];
    }
    *(i32x4*)&Qs[r * 40 + c8] = qv;
    *(i32x4*)&Ks[r * 40 + c8] = kv;
  }
  __syncthreads();

  // QK^T : S[64][64]
  short8 qf[4], kf[4];
  #pragma unroll
  for (int i = 0; i < 4; ++i) qf[i] = *(const short8*)&Qs[(i * 16 + lrow) * 40 + lgrp * 8];
  #pragma unroll
  for (int i = 0; i < 4; ++i) kf[i] = *(const short8*)&Ks[(i * 16 + lrow) * 40 + lgrp * 8];
  f32x4 sc[4][4] = {};
  #pragma unroll
  for (int i = 0; i < 4; ++i)
    #pragma unroll
    for (int j = 0; j < 4; ++j)
      sc[i][j] = __builtin_amdgcn_mfma_f32_16x16x32_bf16(qf[i], kf[j], sc[i][j], 0, 0, 0);

  // bias + mask + softmax (row r held across 16 lanes x 4 col-tiles)
  const float* bp = b12 + h * 2401;
  const float* mp = msk + (b & 15) * 2401;
  float rs[4][4];
  #pragma unroll
  for (int i = 0; i < 4; ++i) {
    #pragma unroll
    for (int j2 = 0; j2 < 4; ++j2) {
      int q = i * 16 + lgrp * 4 + j2;
      float mx = -1e30f;
      #pragma unroll
      for (int j = 0; j < 4; ++j) {
        int kc = j * 16 + lrow;
        float s = sc[i][j][j2];
        if (q < 49 && kc < 49) s += bp[q * 49 + kc] + mp[q * 49 + kc];
        else s = -1e30f;
        sc[i][j][j2] = s;
        mx = fmaxf(mx, s);
      }
      #pragma unroll
      for (int off = 1; off < 16; off <<= 1) mx = fmaxf(mx, __shfl_xor(mx, off));
      float sum = 0.f;
      #pragma unroll
      for (int j = 0; j < 4; ++j) {
        float e = __expf(sc[i][j][j2] - mx);
        sc[i][j][j2] = e;
        sum += e;
      }
      #pragma unroll
      for (int off = 1; off < 16; off <<= 1) sum += __shfl_xor(sum, off);
      rs[i][j2] = sum;
    }
  }
  __syncthreads();   // all Qs/Ks reads done before overlay write
  #pragma unroll
  for (int i = 0; i < 4; ++i)
    #pragma unroll
    for (int j = 0; j < 4; ++j)
      #pragma unroll
      for (int j2 = 0; j2 < 4; ++j2) {
        int q = i * 16 + lgrp * 4 + j2, kc = j * 16 + lrow;
        Ps[q * 72 + kc] = f2bf(sc[i][j][j2]);
      }
  __syncthreads();

  // PV : out[64][32] = P[64][64] @ V[64][32]
  short8 vf[2][2];
  #pragma unroll
  for (int kk = 0; kk < 2; ++kk)
    #pragma unroll
    for (int nl = 0; nl < 2; ++nl)
      vf[kk][nl] = *(const short8*)&Vt[(nl * 16 + lrow) * 72 + kk * 32 + lgrp * 8];
  f32x4 ao[4][2] = {};
  #pragma unroll
  for (int i = 0; i < 4; ++i) {
    short8 pf[2];
    #pragma unroll
    for (int kk = 0; kk < 2; ++kk) pf[kk] = *(const short8*)&Ps[(i * 16 + lrow) * 72 + kk * 32 + lgrp * 8];
    #pragma unroll
    for (int nl = 0; nl < 2; ++nl)
      #pragma unroll
      for (int kk = 0; kk < 2; ++kk)
        ao[i][nl] = __builtin_amdgcn_mfma_f32_16x16x32_bf16(pf[kk], vf[kk][nl], ao[i][nl], 0, 0, 0);
  }

  // epilogue: out[b][s][h*32+d], divide by row sum
  #pragma unroll
  for (int i = 0; i < 4; ++i) {
    #pragma unroll
    for (int j2 = 0; j2 < 4; ++j2) {
      int q = i * 16 + lgrp * 4 + j2;
      if (q < 49) {
        float inv = 1.0f / rs[i][j2];
        #pragma unroll
        for (int nl = 0; nl < 2; ++nl) {
          int d = nl * 16 + lrow;
          out[((size_t)(b * 49 + q)) * 384 + h * 32 + d] = ao[i][nl][j2] * inv;
        }
      }
    }
  }
}

extern "C" void kernel_launch(void* const* d_in, const int* in_sizes, int n_in,
                              void* d_out, int out_size, void* d_ws, size_t ws_size,
                              hipStream_t stream) {
  const float* hs  = (const float*)d_in[0];
  const float* am  = (const float*)d_in[1];
  const float* Wq  = (const float*)d_in[2];
  const float* bq  = (const float*)d_in[3];
  const float* Wk  = (const float*)d_in[4];
  const float* bk  = (const float*)d_in[5];
  const float* Wv  = (const float*)d_in[6];
  const float* bv  = (const float*)d_in[7];
  const float* tab = (const float*)d_in[8];
  const int*   rix = (const int*)d_in[9];
  float* out = (float*)d_out;
  char* ws = (char*)d_ws;

  size_t o = 0;
  auto alloc = [&](size_t bytes) { size_t r = o; o = (o + bytes + 255) & ~(size_t)255; return r; };
  unsigned short* Xb   = (unsigned short*)(ws + alloc(50176ull * 384 * 2));
  unsigned short* Wt   = (unsigned short*)(ws + alloc(1152ull * 384 * 2));
  float*          bvec = (float*)(ws + alloc(1152ull * 4));
  float*          b12  = (float*)(ws + alloc(12ull * 2401 * 4));
  unsigned short* Qb   = (unsigned short*)(ws + alloc(19267584ull * 2));
  unsigned short* Kb   = (unsigned short*)(ws + alloc(19267584ull * 2));
  unsigned short* Vb   = (unsigned short*)(ws + alloc(19267584ull * 2));
  (void)ws_size; (void)in_sizes; (void)n_in; (void)out_size;

  k_convert<<<9408, 256, 0, stream>>>(hs, Xb);
  k_prepw<<<1728, 256, 0, stream>>>(Wq, Wk, Wv, bq, bk, bv, Wt, bvec);
  k_prepb<<<113, 256, 0, stream>>>(tab, rix, b12);
  k_qkv<<<3528, 256, 0, stream>>>(Xb, Wt, bvec, Qb, Kb, Vb);
  k_attn<<<12288, 64, 0, stream>>>(Qb, Kb, Vb, b12, am, out);
}

// Round 2
// 262.515 us; speedup vs baseline: 1.3496x; 1.3496x over previous
//
#include <hip/hip_runtime.h>

typedef __attribute__((ext_vector_type(8))) short short8;
typedef __attribute__((ext_vector_type(4))) float f32x4;
typedef __attribute__((ext_vector_type(4))) int i32x4;

__device__ __forceinline__ unsigned short f2bf(float f) {
  unsigned u = __builtin_bit_cast(unsigned, f);
  u += 0x7fffu + ((u >> 16) & 1u);
  return (unsigned short)(u >> 16);
}

#define GLOAD_LDS16(g, l)                                                              \
  __builtin_amdgcn_global_load_lds(                                                    \
      (const __attribute__((address_space(1))) unsigned int*)(g),                      \
      (__attribute__((address_space(3))) unsigned int*)(l), 16, 0, 0)

// ---------------- convert hidden_states fp32 -> bf16 ----------------
__global__ __launch_bounds__(256) void k_convert(const float* __restrict__ x,
                                                 unsigned short* __restrict__ y) {
  int i = blockIdx.x * 256 + threadIdx.x;   // one thread = 8 elements, exact
  const float* p = x + (size_t)i * 8;
  f32x4 a = *(const f32x4*)p;
  f32x4 b = *(const f32x4*)(p + 4);
  short8 v;
  v[0] = (short)f2bf(a[0]); v[1] = (short)f2bf(a[1]); v[2] = (short)f2bf(a[2]); v[3] = (short)f2bf(a[3]);
  v[4] = (short)f2bf(b[0]); v[5] = (short)f2bf(b[1]); v[6] = (short)f2bf(b[2]); v[7] = (short)f2bf(b[3]);
  *(short8*)(y + (size_t)i * 8) = v;
}

// ---------------- prep: Wt[1152][384] bf16 (transposed, fused QKV), bias[1152] ----------------
__global__ __launch_bounds__(256) void k_prepw(const float* __restrict__ Wq, const float* __restrict__ Wk,
                                               const float* __restrict__ Wv, const float* __restrict__ bq,
                                               const float* __restrict__ bk, const float* __restrict__ bv,
                                               unsigned short* __restrict__ Wt, float* __restrict__ bvec) {
  int i = blockIdx.x * 256 + threadIdx.x;   // 1152*384 = 442368 exact
  int n = i / 384, k = i - n * 384;
  int which = n / 384;                      // 0..2
  int c = n - which * 384;
  const float* W = (which == 0) ? Wq : (which == 1) ? Wk : Wv;
  Wt[i] = f2bf(W[k * 384 + c]);
  if (k == 0) {
    const float* bb = (which == 0) ? bq : (which == 1) ? bk : bv;
    bvec[n] = bb[c];
  }
}

// ---------------- prep: fused bias+mask table in MFMA lane layout ----------------
// T[w][h][jq][ik][lane][r]  (f32x4 per lane): value for q=jq*16+lr, k=ik*16+lg*4+r
__global__ __launch_bounds__(256) void k_prept(const float* __restrict__ tab, const int* __restrict__ ridx,
                                               const float* __restrict__ am, float* __restrict__ T) {
  int i = blockIdx.x * 256 + threadIdx.x;   // 196608 total = 768 blocks
  int lane = i & 63;
  int rest = i >> 6;                        // [wh][jq][ik] : 192*4*4
  int ik = rest & 3, jq = (rest >> 2) & 3, wh = rest >> 4;
  int h = wh % 12, w = wh / 12;
  int lr = lane & 15, lg = lane >> 4;
  int q = jq * 16 + lr;
  f32x4 v;
  #pragma unroll
  for (int r = 0; r < 4; ++r) {
    int k = ik * 16 + lg * 4 + r;
    v[r] = (q < 49 && k < 49) ? tab[ridx[q * 49 + k] * 12 + h] + am[w * 2401 + q * 49 + k] : 0.f;
  }
  *(f32x4*)(T + (size_t)i * 4) = v;
}

// ---------------- QKV GEMM: X[50176,384]bf16 @ Wt^T -> Q,K,V [B,H,S,32] bf16 ----------------
__global__ __launch_bounds__(256) void k_qkv(const unsigned short* __restrict__ X,
                                             const unsigned short* __restrict__ Wt,
                                             const float* __restrict__ bvec,
                                             unsigned short* __restrict__ Qo,
                                             unsigned short* __restrict__ Ko,
                                             unsigned short* __restrict__ Vo) {
  __shared__ __align__(16) unsigned short As[128 * 64];
  __shared__ __align__(16) unsigned short Bs[128 * 64];
  int orig = blockIdx.x;                       // 3528 = 8 * 441
  int wg = (orig & 7) * 441 + (orig >> 3);     // XCD-chunked swizzle (bijective)
  int bm = wg / 9, bn = wg - (wg / 9) * 9;
  int tid = threadIdx.x;
  int lane = tid & 63, wid = tid >> 6;
  int trow = tid >> 3, tcc = tid & 7;          // staging: row within tile / 16B chunk
  const unsigned short* Ag = X + (size_t)(bm * 128) * 384;
  const unsigned short* Bg = Wt + (size_t)(bn * 128) * 384;
  int moff = (wid >> 1) * 64, noff = (wid & 1) * 64;
  int lrow = lane & 15, lgrp = lane >> 4;
  char* AsB = (char*)As + (size_t)wid * 1024;  // wave-uniform LDS dest bases
  char* BsB = (char*)Bs + (size_t)wid * 1024;
  f32x4 acc[4][4] = {};
  for (int ks = 0; ks < 6; ++ks) {
    __syncthreads();
    #pragma unroll
    for (int c = 0; c < 4; ++c) {
      int row = trow + 32 * c;
      int colsw = 8 * (tcc ^ (row & 7)) + ks * 64;   // source pre-swizzle (T2 both-sides)
      GLOAD_LDS16(Ag + (size_t)row * 384 + colsw, AsB + c * 4096);
      GLOAD_LDS16(Bg + (size_t)row * 384 + colsw, BsB + c * 4096);
    }
    __syncthreads();
    #pragma unroll
    for (int hh = 0; hh < 2; ++hh) {
      short8 a[4], b[4];
      #pragma unroll
      for (int i = 0; i < 4; ++i) {
        int ra = moff + i * 16 + lrow;
        a[i] = *(const short8*)&As[ra * 64 + ((lgrp + 4 * hh) ^ (ra & 7)) * 8];
        int rb = noff + i * 16 + lrow;
        b[i] = *(const short8*)&Bs[rb * 64 + ((lgrp + 4 * hh) ^ (rb & 7)) * 8];
      }
      #pragma unroll
      for (int i = 0; i < 4; ++i)
        #pragma unroll
        for (int j = 0; j < 4; ++j)
          acc[i][j] = __builtin_amdgcn_mfma_f32_16x16x32_bf16(a[i], b[j], acc[i][j], 0, 0, 0);
    }
  }
  // epilogue: n-range of this block lies entirely inside one of Q/K/V (384 = 3*128)
  int which = bn / 3;
  unsigned short* Dst = (which == 0) ? Qo : (which == 1) ? Ko : Vo;
  int nbase = bn * 128 - which * 384;
  float scale = (which == 0) ? 0.17677669529663687f : 1.0f;
  #pragma unroll
  for (int i = 0; i < 4; ++i) {
    #pragma unroll
    for (int j2 = 0; j2 < 4; ++j2) {
      int row = moff + i * 16 + lgrp * 4 + j2;
      int gm = bm * 128 + row;
      int bb = gm / 49, ss = gm - bb * 49;
      #pragma unroll
      for (int j = 0; j < 4; ++j) {
        int n = nbase + noff + j * 16 + lrow;   // 0..383 within q/k/v
        int h = n >> 5, d = n & 31;
        float val = (acc[i][j][j2] + bvec[which * 384 + n]) * scale;
        Dst[((size_t)(bb * 12 + h) * 49 + ss) * 32 + d] = f2bf(val);
      }
    }
  }
}

// ---------------- attention: one wave per (b,h); swapped QK^T, in-register softmax ----------------
__global__ __launch_bounds__(64) void k_attn(const unsigned short* __restrict__ Qb,
                                             const unsigned short* __restrict__ Kb,
                                             const unsigned short* __restrict__ Vb,
                                             const float* __restrict__ T,
                                             float* __restrict__ out) {
  __shared__ __align__(16) unsigned short Ps[64 * 64];   // swizzled P rows
  __shared__ __align__(16) unsigned short Vt[32 * 72];   // V^T: Vt[d][s]
  int bh = blockIdx.x;
  int b = bh / 12, h = bh - b * 12;
  int lane = threadIdx.x;
  int lr = lane & 15, lg = lane >> 4;
  const unsigned short* Qg = Qb + (size_t)bh * 1568;
  const unsigned short* Kg = Kb + (size_t)bh * 1568;
  const unsigned short* Vg = Vb + (size_t)bh * 1568;

  // V rows -> regs (4 iters, 4 lanes per row), zero for padded rows
  short8 z = {0, 0, 0, 0, 0, 0, 0, 0};
  short8 vreg[4];
  #pragma unroll
  for (int it = 0; it < 4; ++it) {
    int c = lane + 64 * it;
    int r = c >> 2, c8 = (c & 3) * 8;
    vreg[it] = (r < 49) ? *(const short8*)(Vg + r * 32 + c8) : z;
  }
  // Q,K fragments straight from global (D=32 == MFMA K, no padding needed)
  short8 qf[4], kf[4];
  #pragma unroll
  for (int t = 0; t < 4; ++t) {
    int rq = t * 16 + lr; if (rq > 48) rq = 48;          // clamp: garbage cols discarded
    qf[t] = *(const short8*)(Qg + rq * 32 + lg * 8);
    kf[t] = *(const short8*)(Kg + rq * 32 + lg * 8);
  }
  // S^T = K @ Q^T : lane holds S^T[k=ik*16+lg*4+r][q=jq*16+lr]
  f32x4 sc[4][4] = {};   // [ik][jq]
  #pragma unroll
  for (int ik = 0; ik < 4; ++ik)
    #pragma unroll
    for (int jq = 0; jq < 4; ++jq)
      sc[ik][jq] = __builtin_amdgcn_mfma_f32_16x16x32_bf16(kf[ik], qf[jq], sc[ik][jq], 0, 0, 0);

  // V transpose into LDS (covers s=0..63; zeros for s>=49)
  #pragma unroll
  for (int it = 0; it < 4; ++it) {
    int c = lane + 64 * it;
    int r = c >> 2, c8 = (c & 3) * 8;
    #pragma unroll
    for (int j = 0; j < 8; ++j) Vt[(c8 + j) * 72 + r] = (unsigned short)vreg[it][j];
  }

  // fused bias+mask (precomputed in lane layout) + softmax per q-group jq
  const float* Tb = T + ((size_t)((b & 15) * 12 + h)) * 4096;
  #pragma unroll
  for (int jq = 0; jq < 4; ++jq) {
    #pragma unroll
    for (int ik = 0; ik < 4; ++ik) {
      f32x4 tv = *(const f32x4*)(Tb + ((jq * 4 + ik) * 64 + lane) * 4);
      #pragma unroll
      for (int r = 0; r < 4; ++r) {
        float v = sc[ik][jq][r] + tv[r];
        if (ik == 3) {                                   // k = 48+4*lg+r: valid only lg==0,r==0
          if (r == 0) v = (lg == 0) ? v : -1e30f;
          else v = -1e30f;
        }
        sc[ik][jq][r] = v;
      }
    }
    float m = -1e30f;
    #pragma unroll
    for (int ik = 0; ik < 4; ++ik)
      #pragma unroll
      for (int r = 0; r < 4; ++r) m = fmaxf(m, sc[ik][jq][r]);
    m = fmaxf(m, __shfl_xor(m, 16));
    m = fmaxf(m, __shfl_xor(m, 32));
    float s = 0.f;
    #pragma unroll
    for (int ik = 0; ik < 4; ++ik)
      #pragma unroll
      for (int r = 0; r < 4; ++r) {
        float e = __expf(sc[ik][jq][r] - m);
        sc[ik][jq][r] = e;
        s += e;
      }
    s += __shfl_xor(s, 16);
    s += __shfl_xor(s, 32);
    float iv = 1.0f / s;
    int q = jq * 16 + lr;
    // normalized P -> bf16 quads -> swizzled LDS (b64 writes)
    #pragma unroll
    for (int ik = 0; ik < 4; ++ik) {
      unsigned d0 = (unsigned)f2bf(sc[ik][jq][0] * iv) | ((unsigned)f2bf(sc[ik][jq][1] * iv) << 16);
      unsigned d1 = (unsigned)f2bf(sc[ik][jq][2] * iv) | ((unsigned)f2bf(sc[ik][jq][3] * iv) << 16);
      unsigned off = (unsigned)(q * 128 + ik * 32 + lg * 8) ^ ((unsigned)(lr & 7) << 4);
      *(uint2*)((char*)Ps + off) = make_uint2(d0, d1);
    }
  }
  __syncthreads();

  // PV : out[64][32] = P[64][64] @ V[64][32]
  short8 vf[2][2];
  #pragma unroll
  for (int kk = 0; kk < 2; ++kk)
    #pragma unroll
    for (int nl = 0; nl < 2; ++nl)
      vf[kk][nl] = *(const short8*)&Vt[(nl * 16 + lr) * 72 + kk * 32 + lg * 8];
  f32x4 ao[4][2] = {};
  #pragma unroll
  for (int i = 0; i < 4; ++i) {
    short8 pf[2];
    #pragma unroll
    for (int kk = 0; kk < 2; ++kk) {
      unsigned off = (unsigned)((i * 16 + lr) * 128 + (kk * 4 + lg) * 16) ^ ((unsigned)(lr & 7) << 4);
      pf[kk] = *(const short8*)((char*)Ps + off);
    }
    #pragma unroll
    for (int nl = 0; nl < 2; ++nl)
      #pragma unroll
      for (int kk = 0; kk < 2; ++kk)
        ao[i][nl] = __builtin_amdgcn_mfma_f32_16x16x32_bf16(pf[kk], vf[kk][nl], ao[i][nl], 0, 0, 0);
  }

  // epilogue: out[b][q][h*32+d] (P already normalized)
  #pragma unroll
  for (int i = 0; i < 4; ++i) {
    #pragma unroll
    for (int j2 = 0; j2 < 4; ++j2) {
      int q = i * 16 + lg * 4 + j2;
      if (q < 49) {
        #pragma unroll
        for (int nl = 0; nl < 2; ++nl) {
          int d = nl * 16 + lr;
          out[((size_t)(b * 49 + q)) * 384 + h * 32 + d] = ao[i][nl][j2];
        }
      }
    }
  }
}

extern "C" void kernel_launch(void* const* d_in, const int* in_sizes, int n_in,
                              void* d_out, int out_size, void* d_ws, size_t ws_size,
                              hipStream_t stream) {
  const float* hs  = (const float*)d_in[0];
  const float* am  = (const float*)d_in[1];
  const float* Wq  = (const float*)d_in[2];
  const float* bq  = (const float*)d_in[3];
  const float* Wk  = (const float*)d_in[4];
  const float* bk  = (const float*)d_in[5];
  const float* Wv  = (const float*)d_in[6];
  const float* bv  = (const float*)d_in[7];
  const float* tab = (const float*)d_in[8];
  const int*   rix = (const int*)d_in[9];
  float* out = (float*)d_out;
  char* ws = (char*)d_ws;

  size_t o = 0;
  auto alloc = [&](size_t bytes) { size_t r = o; o = (o + bytes + 255) & ~(size_t)255; return r; };
  unsigned short* Xb   = (unsigned short*)(ws + alloc(50176ull * 384 * 2));
  unsigned short* Wt   = (unsigned short*)(ws + alloc(1152ull * 384 * 2));
  float*          bvec = (float*)(ws + alloc(1152ull * 4));
  float*          Tt   = (float*)(ws + alloc(192ull * 4096 * 4));
  unsigned short* Qb   = (unsigned short*)(ws + alloc(19267584ull * 2));
  unsigned short* Kb   = (unsigned short*)(ws + alloc(19267584ull * 2));
  unsigned short* Vb   = (unsigned short*)(ws + alloc(19267584ull * 2));
  (void)ws_size; (void)in_sizes; (void)n_in; (void)out_size;

  k_convert<<<9408, 256, 0, stream>>>(hs, Xb);
  k_prepw<<<1728, 256, 0, stream>>>(Wq, Wk, Wv, bq, bk, bv, Wt, bvec);
  k_prept<<<768, 256, 0, stream>>>(tab, rix, am, Tt);
  k_qkv<<<3528, 256, 0, stream>>>(Xb, Wt, bvec, Qb, Kb, Vb);
  k_attn<<<12288, 64, 0, stream>>>(Qb, Kb, Vb, Tt, out);
}